// Round 8
// baseline (175.059 us; speedup 1.0000x reference)
//
#include <hip/hip_runtime.h>

#define NP 65536
#define NT 48
#define TH 0.35f
#define PPT 2      // priors per thread in kC
#define KC_BX 128  // kC x-blocks per row (2048 total)
#define NCHUNK 16  // kA prior chunks
#define NCPY 4     // hist contention-spread copies

// ---- ws layout (bytes) ----
// 0       : u64  perchunk[16][48][16]   (per-(row,truth,chunk) best key; dense, no zero needed)
// 98304   : uint hist_cnt[4][16][2048]  -- zeroed by kA
// 622592  : f32  hist_sum[4][16][2048]  -- zeroed by kA
// 1146880 : f32  negsum[16]
// 1147136 : f32  part[2048*8]           {sl,slm,cep,cp,cpl} per kC block
#define PERCHUNK_OFF 0
#define HISTC_OFF    98304
#define HISTS_OFF    622592
#define NEGSUM_OFF   1146880
#define PART_OFF     1147136
#define HIST_DWORDS  262144   // both hist arrays, contiguous

__device__ __forceinline__ float sml1(float d) {
    float a = fabsf(d);
    return a < 1.f ? 0.5f * a * a : a - 0.5f;
}

// ---------------- Kernel A: per-truth argmax over priors ----------------
// grid (16 prior-chunks, 6 truth-groups, 16 rows), block 256.
// Dense per-chunk key writes (no atomics); also zeroes the hist region.
__global__ __launch_bounds__(256) void kA(const float* __restrict__ priors,
                                          const float* __restrict__ targets,
                                          unsigned long long* __restrict__ perchunk,
                                          unsigned int* __restrict__ histz) {
    const int chunk = blockIdx.x, tg = blockIdx.y, b = blockIdx.z;
    // cooperative zero of hist_cnt+hist_sum (1536 blocks x 171 dwords >= 262144)
    {
        int flat = (b * 6 + tg) * NCHUNK + chunk;
        int base = flat * 171 + (int)threadIdx.x;
        if (threadIdx.x < 171 && base < HIST_DWORDS) histz[base] = 0u;
    }
    const float* tb = targets + ((size_t)b * NT + tg * 8) * 15;
    float tx1[8], ty1[8], tx2[8], ty2[8], ta[8];
#pragma unroll
    for (int j = 0; j < 8; j++) {
        tx1[j] = tb[j * 15 + 0]; ty1[j] = tb[j * 15 + 1];
        tx2[j] = tb[j * 15 + 2]; ty2[j] = tb[j * 15 + 3];
        ta[j] = (tx2[j] - tx1[j]) * (ty2[j] - ty1[j]);
    }
    const int pbase = chunk * 4096;
    // track (bi, bs=bi+bu): update is bi'=inter, bs'=S; compare inter*bs > bi*S
    float bi[8], bs[8]; unsigned int bp_[8];
#pragma unroll
    for (int j = 0; j < 8; j++) { bi[j] = 0.f; bs[j] = 1.f; bp_[j] = pbase + threadIdx.x; }
    const float4* P4 = reinterpret_cast<const float4*>(priors);
    for (int i = threadIdx.x; i < 4096; i += 256) {
        const int p = pbase + i;
        const float4 q = P4[p];
        const float px1 = q.x - q.z * 0.5f, py1 = q.y - q.w * 0.5f;
        const float px2 = q.x + q.z * 0.5f, py2 = q.y + q.w * 0.5f;
        const float areaB = (px2 - px1) * (py2 - py1);
#pragma unroll
        for (int j = 0; j < 8; j++) {
            float w = fminf(tx2[j], px2) - fmaxf(tx1[j], px1);
            float h = fminf(ty2[j], py2) - fmaxf(ty1[j], py1);
            w = fmaxf(w, 0.f); h = fmaxf(h, 0.f);
            float inter = w * h;
            float S = ta[j] + areaB;
            if (inter * bs[j] > bi[j] * S) { bi[j] = inter; bs[j] = S; bp_[j] = (unsigned int)p; }
        }
    }
    __shared__ unsigned long long red[4][8];
    const int lane = threadIdx.x & 63, w = threadIdx.x >> 6;
#pragma unroll
    for (int j = 0; j < 8; j++) {
        float bu = bs[j] - bi[j];           // exact union (same rounding as reference)
        float iou = bi[j] / bu;             // exact IEEE div (once per truth, off hot loop)
        unsigned long long key =
            ((unsigned long long)__float_as_uint(iou) << 32) | (unsigned long long)(~bp_[j]);
        for (int s = 32; s > 0; s >>= 1) {
            unsigned long long o = __shfl_down(key, s, 64);
            if (o > key) key = o;
        }
        if (lane == 0) red[w][j] = key;
    }
    __syncthreads();
    if (threadIdx.x < 8) {
        unsigned long long m = red[0][threadIdx.x];
#pragma unroll
        for (int i = 1; i < 4; i++) { unsigned long long o = red[i][threadIdx.x]; if (o > m) m = o; }
        perchunk[((size_t)b * NT + tg * 8 + threadIdx.x) * NCHUNK + chunk] = m;  // dense, no atomic
    }
}

// ---------------- Kernel C: per-prior match, encode, losses, hist cnt+sum ----------------
// grid (128, 16), block 256; 2 priors/thread. No lrank; no contended atomics.
__global__ __launch_bounds__(256) void kC(
    const float* __restrict__ loc_data, const float* __restrict__ conf_data,
    const float* __restrict__ landm_data, const float* __restrict__ priors,
    const float* __restrict__ targets, const unsigned long long* __restrict__ perchunk,
    unsigned int* __restrict__ hist_cnt, float* __restrict__ hist_sum,
    float* __restrict__ part) {
    const int b = blockIdx.y;
    const int bx = blockIdx.x;
    const int p0 = (bx * 256 + threadIdx.x) * PPT;
    const int blockBase = bx * 256 * PPT;

    __shared__ float4 tbox[NT];
    __shared__ float tlab[NT];
    __shared__ float tlm[NT][10];
    __shared__ unsigned int hcnt[2048];
    __shared__ float hsum[2048];
    __shared__ int ccnt;
    __shared__ int clp[NT], clt[NT];

    if (threadIdx.x == 0) ccnt = 0;
#pragma unroll
    for (int i = 0; i < 8; i++) { hcnt[threadIdx.x + i * 256] = 0; hsum[threadIdx.x + i * 256] = 0.f; }
    for (int i = threadIdx.x; i < NT * 15; i += 256) {
        int t = i / 15, f = i - t * 15;
        float v = targets[((size_t)b * NT + t) * 15 + f];
        if (f < 4) reinterpret_cast<float*>(&tbox[t])[f] = v;
        else if (f < 14) tlm[t][f - 4] = v;
        else tlab[t] = v;
    }
    __syncthreads();
    // claim phase: max-reduce 16 chunk keys per truth, compact block-local claims
    if (threadIdx.x < NT) {
        const unsigned long long* pk = perchunk + ((size_t)b * NT + threadIdx.x) * NCHUNK;
        unsigned long long m = pk[0];
#pragma unroll
        for (int c = 1; c < NCHUNK; c++) { unsigned long long o = pk[c]; if (o > m) m = o; }
        int cp = (int)(~(unsigned int)(m & 0xFFFFFFFFull));
        if ((unsigned int)(cp - blockBase) < (unsigned int)(256 * PPT)) {
            int idx = atomicAdd(&ccnt, 1);  // LDS atomic, tiny
            clp[idx] = cp; clt[idx] = threadIdx.x;
        }
    }
    __syncthreads();

    float px1[PPT], py1[PPT], px2[PPT], py2[PPT], aB[PPT];
    float bi[PPT], bs[PPT]; int bt[PPT];
#pragma unroll
    for (int j = 0; j < PPT; j++) {
        float4 q = reinterpret_cast<const float4*>(priors)[p0 + j];
        px1[j] = q.x - q.z * 0.5f; py1[j] = q.y - q.w * 0.5f;
        px2[j] = q.x + q.z * 0.5f; py2[j] = q.y + q.w * 0.5f;
        aB[j] = (px2[j] - px1[j]) * (py2[j] - py1[j]);
        bi[j] = 0.f; bs[j] = 1.f; bt[j] = 0;
    }

    for (int t = 0; t < NT; t++) {
        float4 tb = tbox[t];
        float ta = (tb.z - tb.x) * (tb.w - tb.y);
#pragma unroll
        for (int j = 0; j < PPT; j++) {
            float w = fminf(tb.z, px2[j]) - fmaxf(tb.x, px1[j]);
            float h = fminf(tb.w, py2[j]) - fmaxf(tb.y, py1[j]);
            w = fmaxf(w, 0.f); h = fmaxf(h, 0.f);
            float inter = w * h;
            float S = ta + aB[j];
            if (inter * bs[j] > bi[j] * S) { bi[j] = inter; bs[j] = S; bt[j] = t; }
        }
    }
    bool clf[PPT];
#pragma unroll
    for (int j = 0; j < PPT; j++) clf[j] = false;
    for (int i = 0; i < ccnt; i++) {
        int cp = clp[i], ct = clt[i];
        unsigned int d = (unsigned int)(cp - p0);
        if (d < PPT) {
#pragma unroll
            for (int j = 0; j < PPT; j++) {
                if (d == (unsigned int)j) {
                    bt[j] = clf[j] ? max(bt[j], ct) : ct;
                    clf[j] = true;
                }
            }
        }
    }

    // conf for 2 consecutive priors = one float4
    const float4 cf = reinterpret_cast<const float4*>(conf_data)[((size_t)b * NP + p0) >> 1];
    float cx[PPT] = {cf.x, cf.z};
    float cy[PPT] = {cf.y, cf.w};

    float sl = 0.f, slm = 0.f, cep = 0.f;
    int cp_ = 0, cpl_ = 0;
#pragma unroll
    for (int j = 0; j < PPT; j++) {
        const int btj = bt[j];
        // pos test without division: iou >= TH <=> bi >= TH*(bs-bi); claims force pos
        const bool over = clf[j] || (bi[j] >= TH * (bs[j] - bi[j]));
        const int confi = over ? (int)tlab[btj] : 0;
        const bool pos = (confi != 0);
        const bool posl = (confi > 0);
        float m = fmaxf(cx[j], cy[j]);
        float lse = m + __logf(__expf(cx[j] - m) + __expf(cy[j] - m));
        float ce = lse - (pos ? cy[j] : cx[j]);
        float lr = pos ? 0.f : fmaxf(ce, 0.f);  // clamp: fast-log can give -eps
        unsigned int bin = __float_as_uint(lr) >> 20;
        atomicAdd(&hcnt[bin], 1u);
        if (lr != 0.f) atomicAdd(&hsum[bin], lr);
        if (pos) {
            cep += ce; cp_++;
            float4 q = reinterpret_cast<const float4*>(priors)[p0 + j];
            float4 tb = tbox[btj];
            float izi = 1.f / (0.1f * q.z), iwi = 1.f / (0.1f * q.w);
            float gcx = ((tb.x + tb.z) * 0.5f - q.x) * izi;
            float gcy = ((tb.y + tb.w) * 0.5f - q.y) * iwi;
            float gw = __logf((tb.z - tb.x) / q.z) * 5.f;
            float gh = __logf((tb.w - tb.y) / q.w) * 5.f;
            float4 ld = reinterpret_cast<const float4*>(loc_data)[(size_t)b * NP + p0 + j];
            sl += sml1(ld.x - gcx) + sml1(ld.y - gcy) + sml1(ld.z - gw) + sml1(ld.w - gh);
            if (posl) {
                cpl_++;
                const float* lmd = landm_data + ((size_t)b * NP + p0 + j) * 10;
#pragma unroll
                for (int i = 0; i < 5; i++) {
                    float gx = (tlm[btj][2 * i] - q.x) * izi;
                    float gy = (tlm[btj][2 * i + 1] - q.y) * iwi;
                    slm += sml1(lmd[2 * i] - gx) + sml1(lmd[2 * i + 1] - gy);
                }
            }
        }
    }

    for (int s = 32; s > 0; s >>= 1) {
        sl += __shfl_down(sl, s, 64);
        slm += __shfl_down(slm, s, 64);
        cep += __shfl_down(cep, s, 64);
        cp_ += __shfl_down(cp_, s, 64);
        cpl_ += __shfl_down(cpl_, s, 64);
    }
    __shared__ float rf[12];
    __shared__ int ri[8];
    const int lane = threadIdx.x & 63, w = threadIdx.x >> 6;
    if (lane == 0) { rf[w] = sl; rf[4 + w] = slm; rf[8 + w] = cep; ri[w] = cp_; ri[4 + w] = cpl_; }
    __syncthreads();
    if (threadIdx.x == 0) {
        float a = 0, bb = 0, c = 0; int d = 0, e = 0;
        for (int i = 0; i < 4; i++) { a += rf[i]; bb += rf[4 + i]; c += rf[8 + i]; d += ri[i]; e += ri[4 + i]; }
        float* pp = part + ((size_t)b * KC_BX + bx) * 8;   // private slot
        pp[0] = a; pp[1] = bb; pp[2] = c; pp[3] = (float)d; pp[4] = (float)e;
    }
    // hist merge into contention-spread copies (skip empties)
    {
        const unsigned int cidx = ((unsigned int)(bx & (NCPY - 1)) * 16 + b) << 11;
        unsigned int* gc = hist_cnt + cidx;
        float* gs = hist_sum + cidx;
#pragma unroll
        for (int i = 0; i < 8; i++) {
            unsigned int c = hcnt[threadIdx.x + i * 256];
            if (c) atomicAdd(&gc[threadIdx.x + i * 256], c);
            float s = hsum[threadIdx.x + i * 256];
            if (s != 0.f) atomicAdd(&gs[threadIdx.x + i * 256], s);
        }
    }
}

// ---------------- Kernel F: closed-form top-k negative sum from hist ----------------
// grid 16 (one block per row), block 256. No lrank scan.
__global__ __launch_bounds__(256) void kF(const unsigned int* __restrict__ hist_cnt,
                                          const float* __restrict__ hist_sum,
                                          const float* __restrict__ part,
                                          float* __restrict__ negsum) {
    const int b = blockIdx.x;
    __shared__ float pk[2];
    __shared__ unsigned int shc[2048];
    __shared__ float shs[2048];
    __shared__ unsigned int ps[256];
    __shared__ int sbin;
    __shared__ unsigned int sacc;
    __shared__ float wsum[4];

    // npos over this row's 128 part slots
    {
        float v = (threadIdx.x < KC_BX)
                      ? part[((size_t)b * KC_BX + threadIdx.x) * 8 + 3] : 0.f;
        for (int s = 32; s > 0; s >>= 1) v += __shfl_down(v, s, 64);
        if ((threadIdx.x & 63) == 0 && threadIdx.x < 128) pk[threadIdx.x >> 6] = v;
    }
    // merge hist copies into LDS
    for (int off = 0; off < 2048; off += 256) {
        unsigned int c = 0; float s = 0.f;
#pragma unroll
        for (int cp = 0; cp < NCPY; cp++) {
            unsigned int idx = (((unsigned int)cp * 16 + b) << 11) + off + threadIdx.x;
            c += hist_cnt[idx];
            s += hist_sum[idx];
        }
        shc[off + threadIdx.x] = c;
        shs[off + threadIdx.x] = s;
    }
    __syncthreads();
    int k = 7 * (int)(pk[0] + pk[1] + 0.5f);
    if (k > NP - 1) k = NP - 1;
    if (k <= 0) { if (threadIdx.x == 0) negsum[b] = 0.f; return; }

    {
        unsigned int s = 0;
#pragma unroll
        for (int i = 0; i < 8; i++) s += shc[threadIdx.x * 8 + i];
        ps[threadIdx.x] = s;
    }
    __syncthreads();
    if (threadIdx.x == 0) {
        unsigned int kk = (unsigned int)k, acc = 0; int g = 255;
        for (; g > 0; --g) { unsigned int pg = ps[g]; if (acc + pg >= kk) break; acc += pg; }
        int bin = g * 8;
        for (int i = 7; i >= 0; --i) {
            unsigned int c = shc[g * 8 + i];
            if (acc + c >= kk) { bin = g * 8 + i; break; }
            acc += c;
        }
        sbin = bin; sacc = acc;  // acc = count strictly above bin
    }
    __syncthreads();
    const int b1 = sbin;
    float sum = 0.f;
    for (int i = threadIdx.x; i < 2048; i += 256)
        if (i > b1) sum += shs[i];               // exact sum of all strictly-above-bin values
    for (int s = 32; s > 0; s >>= 1) sum += __shfl_down(sum, s, 64);
    const int lane = threadIdx.x & 63, w = threadIdx.x >> 6;
    if (lane == 0) wsum[w] = sum;
    __syncthreads();
    if (threadIdx.x == 0) {
        float tot = wsum[0] + wsum[1] + wsum[2] + wsum[3];
        // boundary-bin members at bin midpoint (rel err <= 6.25% of one bin's term)
        unsigned int k2 = (unsigned int)k - sacc;
        tot += (float)k2 * __uint_as_float(((unsigned int)b1 << 20) | 0x80000u);
        negsum[b] = tot;
    }
}

// ---------------- Kernel E: final reduce (2048 partial slots + 16 negsum) ----------------
__global__ __launch_bounds__(1024) void kE(const float* __restrict__ part,
                                           const float* __restrict__ negsum,
                                           float* __restrict__ out) {
    float sl = 0.f, slm = 0.f, cep = 0.f, cp = 0.f, cpl = 0.f;
#pragma unroll
    for (int r = 0; r < 2; r++) {
        const float* pp = part + ((size_t)threadIdx.x + r * 1024) * 8;
        sl += pp[0]; slm += pp[1]; cep += pp[2]; cp += pp[3]; cpl += pp[4];
    }
    float ns = (threadIdx.x < 16) ? negsum[threadIdx.x] : 0.f;
    for (int s = 32; s > 0; s >>= 1) {
        sl += __shfl_down(sl, s, 64);
        slm += __shfl_down(slm, s, 64);
        cep += __shfl_down(cep, s, 64);
        cp += __shfl_down(cp, s, 64);
        cpl += __shfl_down(cpl, s, 64);
        ns += __shfl_down(ns, s, 64);
    }
    __shared__ float r_[16][6];
    const int lane = threadIdx.x & 63, w = threadIdx.x >> 6;
    if (lane == 0) {
        r_[w][0] = sl; r_[w][1] = slm; r_[w][2] = cep;
        r_[w][3] = cp; r_[w][4] = cpl; r_[w][5] = ns;
    }
    __syncthreads();
    if (threadIdx.x == 0) {
        float a = 0, bb = 0, c = 0, d = 0, e = 0, n = 0;
        for (int i = 0; i < 16; i++) {
            a += r_[i][0]; bb += r_[i][1]; c += r_[i][2];
            d += r_[i][3]; e += r_[i][4]; n += r_[i][5];
        }
        float N = fmaxf(d, 1.f);
        float N1 = fmaxf(e, 1.f);
        out[0] = a / N;
        out[1] = (c + n) / N;
        out[2] = bb / N1;
    }
}

extern "C" void kernel_launch(void* const* d_in, const int* in_sizes, int n_in,
                              void* d_out, int out_size, void* d_ws, size_t ws_size,
                              hipStream_t stream) {
    const float* loc_data = (const float*)d_in[0];
    const float* conf_data = (const float*)d_in[1];
    const float* landm_data = (const float*)d_in[2];
    const float* priors = (const float*)d_in[3];
    const float* targets = (const float*)d_in[4];
    float* out = (float*)d_out;
    char* ws = (char*)d_ws;
    unsigned long long* perchunk = (unsigned long long*)(ws + PERCHUNK_OFF);
    unsigned int* hist_cnt = (unsigned int*)(ws + HISTC_OFF);
    float* hist_sum = (float*)(ws + HISTS_OFF);
    float* negsum = (float*)(ws + NEGSUM_OFF);
    float* part = (float*)(ws + PART_OFF);

    // no memset: kA zeroes the hist region (stream-ordered before kC);
    // perchunk/part/negsum are fully overwritten each launch.
    kA<<<dim3(NCHUNK, 6, 16), 256, 0, stream>>>(priors, targets, perchunk, hist_cnt);
    kC<<<dim3(KC_BX, 16), 256, 0, stream>>>(loc_data, conf_data, landm_data, priors, targets,
                                            perchunk, hist_cnt, hist_sum, part);
    kF<<<16, 256, 0, stream>>>(hist_cnt, hist_sum, part, negsum);
    kE<<<1, 1024, 0, stream>>>(part, negsum, out);
}

// Round 9
// 164.735 us; speedup vs baseline: 1.0627x; 1.0627x over previous
//
#include <hip/hip_runtime.h>

#define NP 65536
#define NT 48
#define TH 0.35f
#define PPT 2      // priors per thread in kC
#define KC_BX 128  // kC x-blocks per row (2048 total)
#define NCHUNK 16  // kA prior chunks
#define NCPY 2     // hist contention-spread copies

// ---- ws layout (bytes) ----
// 0      : u64  perchunk[16][48][16]   (dense per-(row,truth,chunk) keys; fully overwritten)
// 98304  : f32  accf[8]  {sl,slm,cep,cp,cpl,neg}          -- zeroed by kA
// 98336  : u32  done_cnt                                   -- zeroed by kA
// 98368  : uint hist_cnt[2][16][2048]                      -- zeroed by kA
// 360512 : f32  hist_sum[2][16][2048]                      -- zeroed by kA
// 622656 : f32  part[2048*8]           (fully overwritten)
#define PERCHUNK_OFF 0
#define ACCF_OFF     98304
#define DONE_OFF     98336
#define HISTC_OFF    98368
#define HISTS_OFF    360512
#define PART_OFF     622656
#define ZERO_DWORDS  131088   // accf..hist_sum end = 524352 bytes

__device__ __forceinline__ float sml1(float d) {
    float a = fabsf(d);
    return a < 1.f ? 0.5f * a * a : a - 0.5f;
}

// ---------------- Kernel A: per-truth argmax over priors ----------------
// grid (16 prior-chunks, 6 truth-groups, 16 rows), block 256.
// Dense per-chunk key writes (no atomics); also zeroes accf/done/hist region.
__global__ __launch_bounds__(256) void kA(const float* __restrict__ priors,
                                          const float* __restrict__ targets,
                                          unsigned long long* __restrict__ perchunk,
                                          unsigned int* __restrict__ zbase) {
    const int chunk = blockIdx.x, tg = blockIdx.y, b = blockIdx.z;
    // cooperative zero: 1536 blocks x 96 dwords >= 131088
    {
        int flat = (b * 6 + tg) * NCHUNK + chunk;
        int base = flat * 96 + (int)threadIdx.x;
        if (threadIdx.x < 96 && base < ZERO_DWORDS) zbase[base] = 0u;
    }
    const float* tb = targets + ((size_t)b * NT + tg * 8) * 15;
    float tx1[8], ty1[8], tx2[8], ty2[8], ta[8];
#pragma unroll
    for (int j = 0; j < 8; j++) {
        tx1[j] = tb[j * 15 + 0]; ty1[j] = tb[j * 15 + 1];
        tx2[j] = tb[j * 15 + 2]; ty2[j] = tb[j * 15 + 3];
        ta[j] = (tx2[j] - tx1[j]) * (ty2[j] - ty1[j]);
    }
    const int pbase = chunk * 4096;
    // track (bi, bs=bi+bu): update is bi'=inter, bs'=S; compare inter*bs > bi*S
    float bi[8], bs[8]; unsigned int bp_[8];
#pragma unroll
    for (int j = 0; j < 8; j++) { bi[j] = 0.f; bs[j] = 1.f; bp_[j] = pbase + threadIdx.x; }
    const float4* P4 = reinterpret_cast<const float4*>(priors);
    for (int i = threadIdx.x; i < 4096; i += 256) {
        const int p = pbase + i;
        const float4 q = P4[p];
        const float px1 = q.x - q.z * 0.5f, py1 = q.y - q.w * 0.5f;
        const float px2 = q.x + q.z * 0.5f, py2 = q.y + q.w * 0.5f;
        const float areaB = (px2 - px1) * (py2 - py1);
#pragma unroll
        for (int j = 0; j < 8; j++) {
            float w = fminf(tx2[j], px2) - fmaxf(tx1[j], px1);
            float h = fminf(ty2[j], py2) - fmaxf(ty1[j], py1);
            w = fmaxf(w, 0.f); h = fmaxf(h, 0.f);
            float inter = w * h;
            float S = ta[j] + areaB;
            if (inter * bs[j] > bi[j] * S) { bi[j] = inter; bs[j] = S; bp_[j] = (unsigned int)p; }
        }
    }
    __shared__ unsigned long long red[4][8];
    const int lane = threadIdx.x & 63, w = threadIdx.x >> 6;
#pragma unroll
    for (int j = 0; j < 8; j++) {
        float bu = bs[j] - bi[j];           // exact union
        float iou = bi[j] / bu;             // exact IEEE div, off hot loop
        unsigned long long key =
            ((unsigned long long)__float_as_uint(iou) << 32) | (unsigned long long)(~bp_[j]);
        for (int s = 32; s > 0; s >>= 1) {
            unsigned long long o = __shfl_down(key, s, 64);
            if (o > key) key = o;
        }
        if (lane == 0) red[w][j] = key;
    }
    __syncthreads();
    if (threadIdx.x < 8) {
        unsigned long long m = red[0][threadIdx.x];
#pragma unroll
        for (int i = 1; i < 4; i++) { unsigned long long o = red[i][threadIdx.x]; if (o > m) m = o; }
        perchunk[((size_t)b * NT + tg * 8 + threadIdx.x) * NCHUNK + chunk] = m;  // dense, no atomic
    }
}

// ---------------- Kernel C: per-prior match, encode, losses, hist cnt+sum ----------------
// grid (128, 16), block 256; 2 priors/thread. No contended atomics.
__global__ __launch_bounds__(256) void kC(
    const float* __restrict__ loc_data, const float* __restrict__ conf_data,
    const float* __restrict__ landm_data, const float* __restrict__ priors,
    const float* __restrict__ targets, const unsigned long long* __restrict__ perchunk,
    unsigned int* __restrict__ hist_cnt, float* __restrict__ hist_sum,
    float* __restrict__ part) {
    const int b = blockIdx.y;
    const int bx = blockIdx.x;
    const int p0 = (bx * 256 + threadIdx.x) * PPT;
    const int blockBase = bx * 256 * PPT;

    __shared__ float4 tbox[NT];
    __shared__ float tarea[NT];
    __shared__ float tlab[NT];
    __shared__ float tlm[NT][10];
    __shared__ unsigned int hcnt[2048];
    __shared__ float hsum[2048];
    __shared__ int ccnt;
    __shared__ int clp[NT], clt[NT];

    if (threadIdx.x == 0) ccnt = 0;
    // vectorizable hist zero: each thread owns 8 consecutive bins in each array
    {
        const int hb = threadIdx.x * 8;
#pragma unroll
        for (int i = 0; i < 8; i++) { hcnt[hb + i] = 0; hsum[hb + i] = 0.f; }
    }
    for (int i = threadIdx.x; i < NT * 15; i += 256) {
        int t = i / 15, f = i - t * 15;
        float v = targets[((size_t)b * NT + t) * 15 + f];
        if (f < 4) reinterpret_cast<float*>(&tbox[t])[f] = v;
        else if (f < 14) tlm[t][f - 4] = v;
        else tlab[t] = v;
    }
    __syncthreads();
    // phase 1: truth areas + claim compaction (max over 16 chunk keys per truth)
    if (threadIdx.x < NT) {
        float4 tb = tbox[threadIdx.x];
        tarea[threadIdx.x] = (tb.z - tb.x) * (tb.w - tb.y);
        const unsigned long long* pk = perchunk + ((size_t)b * NT + threadIdx.x) * NCHUNK;
        unsigned long long m = pk[0];
#pragma unroll
        for (int c = 1; c < NCHUNK; c++) { unsigned long long o = pk[c]; if (o > m) m = o; }
        int cp = (int)(~(unsigned int)(m & 0xFFFFFFFFull));
        if ((unsigned int)(cp - blockBase) < (unsigned int)(256 * PPT)) {
            int idx = atomicAdd(&ccnt, 1);  // LDS atomic, tiny
            clp[idx] = cp; clt[idx] = threadIdx.x;
        }
    }
    __syncthreads();

    float px1[PPT], py1[PPT], px2[PPT], py2[PPT], aB[PPT];
    float bi[PPT], bs[PPT]; int bt[PPT];
#pragma unroll
    for (int j = 0; j < PPT; j++) {
        float4 q = reinterpret_cast<const float4*>(priors)[p0 + j];
        px1[j] = q.x - q.z * 0.5f; py1[j] = q.y - q.w * 0.5f;
        px2[j] = q.x + q.z * 0.5f; py2[j] = q.y + q.w * 0.5f;
        aB[j] = (px2[j] - px1[j]) * (py2[j] - py1[j]);
        bi[j] = 0.f; bs[j] = 1.f; bt[j] = 0;
    }

#pragma unroll 4
    for (int t = 0; t < NT; t++) {
        float4 tb = tbox[t];
        float ta = tarea[t];
#pragma unroll
        for (int j = 0; j < PPT; j++) {
            float w = fminf(tb.z, px2[j]) - fmaxf(tb.x, px1[j]);
            float h = fminf(tb.w, py2[j]) - fmaxf(tb.y, py1[j]);
            w = fmaxf(w, 0.f); h = fmaxf(h, 0.f);
            float inter = w * h;
            float S = ta + aB[j];
            if (inter * bs[j] > bi[j] * S) { bi[j] = inter; bs[j] = S; bt[j] = t; }
        }
    }
    bool clf[PPT];
#pragma unroll
    for (int j = 0; j < PPT; j++) clf[j] = false;
    for (int i = 0; i < ccnt; i++) {
        int cp = clp[i], ct = clt[i];
        unsigned int d = (unsigned int)(cp - p0);
        if (d < PPT) {
#pragma unroll
            for (int j = 0; j < PPT; j++) {
                if (d == (unsigned int)j) {
                    bt[j] = clf[j] ? max(bt[j], ct) : ct;
                    clf[j] = true;
                }
            }
        }
    }

    // conf for 2 consecutive priors = one float4
    const float4 cf = reinterpret_cast<const float4*>(conf_data)[((size_t)b * NP + p0) >> 1];
    float cx[PPT] = {cf.x, cf.z};
    float cy[PPT] = {cf.y, cf.w};

    float sl = 0.f, slm = 0.f, cep = 0.f;
    int cp_ = 0, cpl_ = 0;
#pragma unroll
    for (int j = 0; j < PPT; j++) {
        const int btj = bt[j];
        // pos test without division: iou >= TH <=> bi >= TH*(bs-bi); claims force pos
        const bool over = clf[j] || (bi[j] >= TH * (bs[j] - bi[j]));
        const int confi = over ? (int)tlab[btj] : 0;
        const bool pos = (confi != 0);
        const bool posl = (confi > 0);
        // single-exp logsumexp over 2 classes: m + log1p(exp(-|cx-cy|))
        float m = fmaxf(cx[j], cy[j]);
        float lse = m + __logf(1.f + __expf(-fabsf(cx[j] - cy[j])));
        float ce = lse - (pos ? cy[j] : cx[j]);
        float lr = pos ? 0.f : fmaxf(ce, 0.f);  // clamp: fast-log can give -eps
        unsigned int bin = __float_as_uint(lr) >> 20;
        atomicAdd(&hcnt[bin], 1u);
        if (lr != 0.f) atomicAdd(&hsum[bin], lr);
        if (pos) {
            cep += ce; cp_++;
            float4 q = reinterpret_cast<const float4*>(priors)[p0 + j];
            float4 tb = tbox[btj];
            float izi = 1.f / (0.1f * q.z), iwi = 1.f / (0.1f * q.w);
            float gcx = ((tb.x + tb.z) * 0.5f - q.x) * izi;
            float gcy = ((tb.y + tb.w) * 0.5f - q.y) * iwi;
            float gw = __logf((tb.z - tb.x) / q.z) * 5.f;
            float gh = __logf((tb.w - tb.y) / q.w) * 5.f;
            float4 ld = reinterpret_cast<const float4*>(loc_data)[(size_t)b * NP + p0 + j];
            sl += sml1(ld.x - gcx) + sml1(ld.y - gcy) + sml1(ld.z - gw) + sml1(ld.w - gh);
            if (posl) {
                cpl_++;
                const float* lmd = landm_data + ((size_t)b * NP + p0 + j) * 10;
#pragma unroll
                for (int i = 0; i < 5; i++) {
                    float gx = (tlm[btj][2 * i] - q.x) * izi;
                    float gy = (tlm[btj][2 * i + 1] - q.y) * iwi;
                    slm += sml1(lmd[2 * i] - gx) + sml1(lmd[2 * i + 1] - gy);
                }
            }
        }
    }

    for (int s = 32; s > 0; s >>= 1) {
        sl += __shfl_down(sl, s, 64);
        slm += __shfl_down(slm, s, 64);
        cep += __shfl_down(cep, s, 64);
        cp_ += __shfl_down(cp_, s, 64);
        cpl_ += __shfl_down(cpl_, s, 64);
    }
    __shared__ float rf[12];
    __shared__ int ri[8];
    const int lane = threadIdx.x & 63, w = threadIdx.x >> 6;
    if (lane == 0) { rf[w] = sl; rf[4 + w] = slm; rf[8 + w] = cep; ri[w] = cp_; ri[4 + w] = cpl_; }
    __syncthreads();
    if (threadIdx.x == 0) {
        float a = 0, bb = 0, c = 0; int d = 0, e = 0;
        for (int i = 0; i < 4; i++) { a += rf[i]; bb += rf[4 + i]; c += rf[8 + i]; d += ri[i]; e += ri[4 + i]; }
        float* pp = part + ((size_t)b * KC_BX + bx) * 8;   // private slot
        pp[0] = a; pp[1] = bb; pp[2] = c; pp[3] = (float)d; pp[4] = (float)e;
    }
    // hist merge into contention-spread copies (skip empties)
    {
        const unsigned int cidx = ((unsigned int)(bx & (NCPY - 1)) * 16 + b) << 11;
        unsigned int* gc = hist_cnt + cidx;
        float* gs = hist_sum + cidx;
#pragma unroll
        for (int i = 0; i < 8; i++) {
            unsigned int c = hcnt[threadIdx.x + i * 256];
            if (c) atomicAdd(&gc[threadIdx.x + i * 256], c);
            float s = hsum[threadIdx.x + i * 256];
            if (s != 0.f) atomicAdd(&gs[threadIdx.x + i * 256], s);
        }
    }
}

// ---------------- Kernel F: per-row reduce + closed-form top-k neg sum + finalize ----------------
// grid 16 (one block per row), block 256. Last-arriving block writes out.
__global__ __launch_bounds__(256) void kF(const unsigned int* __restrict__ hist_cnt,
                                          const float* __restrict__ hist_sum,
                                          const float* __restrict__ part,
                                          float* __restrict__ accf,
                                          unsigned int* __restrict__ done_cnt,
                                          float* __restrict__ out) {
    const int b = blockIdx.x;
    __shared__ float rsum[2][5];
    __shared__ unsigned int shc[2048];
    __shared__ float shs[2048];
    __shared__ unsigned int ps[256];
    __shared__ int sbin;
    __shared__ unsigned int sacc;
    __shared__ float wsum[4];

    // reduce this row's 128 part slots (5 values each)
    {
        float v0 = 0, v1 = 0, v2 = 0, v3 = 0, v4 = 0;
        if (threadIdx.x < KC_BX) {
            const float* pp = part + ((size_t)b * KC_BX + threadIdx.x) * 8;
            v0 = pp[0]; v1 = pp[1]; v2 = pp[2]; v3 = pp[3]; v4 = pp[4];
        }
        for (int s = 32; s > 0; s >>= 1) {
            v0 += __shfl_down(v0, s, 64);
            v1 += __shfl_down(v1, s, 64);
            v2 += __shfl_down(v2, s, 64);
            v3 += __shfl_down(v3, s, 64);
            v4 += __shfl_down(v4, s, 64);
        }
        if ((threadIdx.x & 63) == 0 && threadIdx.x < 128) {
            int w = threadIdx.x >> 6;
            rsum[w][0] = v0; rsum[w][1] = v1; rsum[w][2] = v2; rsum[w][3] = v3; rsum[w][4] = v4;
        }
    }
    // merge hist copies into LDS
    for (int off = 0; off < 2048; off += 256) {
        unsigned int c = 0; float s = 0.f;
#pragma unroll
        for (int cp = 0; cp < NCPY; cp++) {
            unsigned int idx = (((unsigned int)cp * 16 + b) << 11) + off + threadIdx.x;
            c += hist_cnt[idx];
            s += hist_sum[idx];
        }
        shc[off + threadIdx.x] = c;
        shs[off + threadIdx.x] = s;
    }
    __syncthreads();
    int k = 7 * (int)(rsum[0][3] + rsum[1][3] + 0.5f);
    if (k > NP - 1) k = NP - 1;
    if (k < 0) k = 0;   // kk=0 degenerates safely to tot=0 below

    {
        unsigned int s = 0;
#pragma unroll
        for (int i = 0; i < 8; i++) s += shc[threadIdx.x * 8 + i];
        ps[threadIdx.x] = s;
    }
    __syncthreads();
    if (threadIdx.x == 0) {
        unsigned int kk = (unsigned int)k, acc = 0; int g = 255;
        for (; g > 0; --g) { unsigned int pg = ps[g]; if (acc + pg >= kk) break; acc += pg; }
        int bin = g * 8;
        for (int i = 7; i >= 0; --i) {
            unsigned int c = shc[g * 8 + i];
            if (acc + c >= kk) { bin = g * 8 + i; break; }
            acc += c;
        }
        sbin = bin; sacc = acc;  // acc = count strictly above bin
    }
    __syncthreads();
    const int b1 = sbin;
    float sum = 0.f;
    for (int i = threadIdx.x; i < 2048; i += 256)
        if (i > b1) sum += shs[i];               // exact sum of strictly-above-bin values
    for (int s = 32; s > 0; s >>= 1) sum += __shfl_down(sum, s, 64);
    const int lane = threadIdx.x & 63, w = threadIdx.x >> 6;
    if (lane == 0) wsum[w] = sum;
    __syncthreads();
    if (threadIdx.x == 0) {
        float tot = wsum[0] + wsum[1] + wsum[2] + wsum[3];
        // boundary-bin members at bin midpoint (rel err <= 6.25% of one bin's term)
        unsigned int k2 = (unsigned int)k - sacc;
        if (k > 0) tot += (float)k2 * __uint_as_float(((unsigned int)b1 << 20) | 0x80000u);
        // accumulate row results (16 blocks x 6 atomics: contention-free)
        atomicAdd(&accf[0], rsum[0][0] + rsum[1][0]);  // sl
        atomicAdd(&accf[1], rsum[0][1] + rsum[1][1]);  // slm
        atomicAdd(&accf[2], rsum[0][2] + rsum[1][2]);  // cep
        atomicAdd(&accf[3], rsum[0][3] + rsum[1][3]);  // cp
        atomicAdd(&accf[4], rsum[0][4] + rsum[1][4]);  // cpl
        atomicAdd(&accf[5], tot);                      // negsum
        __threadfence();
        unsigned int prev = atomicAdd(done_cnt, 1u);
        if (prev == 15u) {
            __threadfence();
            float a  = atomicAdd(&accf[0], 0.f);
            float bb = atomicAdd(&accf[1], 0.f);
            float c  = atomicAdd(&accf[2], 0.f);
            float d  = atomicAdd(&accf[3], 0.f);
            float e  = atomicAdd(&accf[4], 0.f);
            float n  = atomicAdd(&accf[5], 0.f);
            float N = fmaxf(d, 1.f);
            float N1 = fmaxf(e, 1.f);
            out[0] = a / N;
            out[1] = (c + n) / N;
            out[2] = bb / N1;
        }
    }
}

extern "C" void kernel_launch(void* const* d_in, const int* in_sizes, int n_in,
                              void* d_out, int out_size, void* d_ws, size_t ws_size,
                              hipStream_t stream) {
    const float* loc_data = (const float*)d_in[0];
    const float* conf_data = (const float*)d_in[1];
    const float* landm_data = (const float*)d_in[2];
    const float* priors = (const float*)d_in[3];
    const float* targets = (const float*)d_in[4];
    float* out = (float*)d_out;
    char* ws = (char*)d_ws;
    unsigned long long* perchunk = (unsigned long long*)(ws + PERCHUNK_OFF);
    float* accf = (float*)(ws + ACCF_OFF);
    unsigned int* done_cnt = (unsigned int*)(ws + DONE_OFF);
    unsigned int* hist_cnt = (unsigned int*)(ws + HISTC_OFF);
    float* hist_sum = (float*)(ws + HISTS_OFF);
    float* part = (float*)(ws + PART_OFF);

    // kA zeroes accf/done/hist (stream-ordered before kC/kF); rest fully overwritten.
    kA<<<dim3(NCHUNK, 6, 16), 256, 0, stream>>>(priors, targets, perchunk,
                                                (unsigned int*)(ws + ACCF_OFF));
    kC<<<dim3(KC_BX, 16), 256, 0, stream>>>(loc_data, conf_data, landm_data, priors, targets,
                                            perchunk, hist_cnt, hist_sum, part);
    kF<<<16, 256, 0, stream>>>(hist_cnt, hist_sum, part, accf, done_cnt, out);
}